// Round 1
// baseline (36781.647 us; speedup 1.0000x reference)
//
#include <hip/hip_runtime.h>

typedef float f32x2 __attribute__((ext_vector_type(2)));

static constexpr int T_LEN  = 262144;
static constexpr int NCHUNK = T_LEN / 64;   // 4096

__device__ __forceinline__ float sigm_f(float x) {
    // 1/(1+2^(-x*log2e)); saturates correctly at +-inf
    return __builtin_amdgcn_rcpf(1.0f + __builtin_amdgcn_exp2f(-1.4426950408889634f * x));
}
__device__ __forceinline__ float tanh_f(float x) {
    // 1 - 2/(2^(x*2*log2e)+1); saturates correctly at +-inf
    return 1.0f - 2.0f * __builtin_amdgcn_rcpf(1.0f + __builtin_amdgcn_exp2f(2.8853900817779268f * x));
}
__device__ __forceinline__ float readlane_f(float v, int srcLane) {
    return __builtin_bit_cast(float, __builtin_amdgcn_readlane(__builtin_bit_cast(int, v), srcLane));
}
__device__ __forceinline__ float bperm_f(int byteAddr, float v) {
    return __builtin_bit_cast(float, __builtin_amdgcn_ds_bpermute(byteAddr, __builtin_bit_cast(int, v)));
}
template <int CTRL>
__device__ __forceinline__ float qperm_f(float v) {
    // DPP quad_perm broadcast within each 4-lane group
    return __builtin_bit_cast(float, __builtin_amdgcn_update_dpp(
        0, __builtin_bit_cast(int, v), CTRL, 0xF, 0xF, true));
}

__global__ __launch_bounds__(64, 1)
void lstm10_h4_kernel(const float* __restrict__ x,
                      const float* __restrict__ W_ih0,
                      const float* __restrict__ W_ih,
                      const float* __restrict__ W_hh,
                      const float* __restrict__ b_ih,
                      const float* __restrict__ b_hh,
                      const float* __restrict__ W_fc,
                      const float* __restrict__ b_fc,
                      float* __restrict__ out)
{
    __shared__ float hFinal[64];

    const int lane = threadIdx.x;
    const int L  = lane >> 2;            // layer 0..15 (10..15 are scratch lanes)
    const int j  = lane & 3;             // hidden unit
    const int Lc = (L < 10) ? L : 9;     // clamp for weight loads (scratch lanes)
    const bool isL0 = (L == 0);

    // gate rows for hidden unit j: i=rows[0:4], f=[4:8], g=[8:12], o=[12:16]
    const int ri = j, rf = 4 + j, rg = 8 + j, ro = 12 + j;

    // Packed weights: wif[k] = {W[i_row][k], W[f_row][k]}, k=0..3 input cols, 4..7 hh cols
    f32x2 wif[8], wgo[8];
    if (Lc == 0) {
        wif[0] = {W_ih0[ri], W_ih0[rf]};
        wgo[0] = {W_ih0[rg], W_ih0[ro]};
        #pragma unroll
        for (int k = 1; k < 4; ++k) { wif[k] = {0.f, 0.f}; wgo[k] = {0.f, 0.f}; }
    } else {
        const float* B = W_ih + (Lc - 1) * 64;
        #pragma unroll
        for (int k = 0; k < 4; ++k) {
            wif[k] = {B[ri*4+k], B[rf*4+k]};
            wgo[k] = {B[rg*4+k], B[ro*4+k]};
        }
    }
    {
        const float* B = W_hh + Lc * 64;
        #pragma unroll
        for (int k = 0; k < 4; ++k) {
            wif[4+k] = {B[ri*4+k], B[rf*4+k]};
            wgo[4+k] = {B[rg*4+k], B[ro*4+k]};
        }
    }
    const float* bi = b_ih + Lc * 16;
    const float* bh = b_hh + Lc * 16;
    f32x2 bif = {bi[ri] + bh[ri], bi[rf] + bh[rf]};
    f32x2 bgo = {bi[rg] + bh[rg], bi[ro] + bh[ro]};

    // bpermute byte-address of lane 4*(L-1) (lower layer's quad)
    const int lowBase = ((L > 0 ? L - 1 : 0) * 4) << 2;

    float c = 0.0f, h = 0.0f;

    auto doStep = [&](float xt, bool active) {
        // own-layer h quad via DPP (fast, register-only)
        float h0 = qperm_f<0x00>(h);
        float h1 = qperm_f<0x55>(h);
        float h2 = qperm_f<0xAA>(h);
        float h3 = qperm_f<0xFF>(h);
        // lower-layer h quad via ds_bpermute (no LDS storage, no barrier)
        float p0 = bperm_f(lowBase + 0,  h);
        float p1 = bperm_f(lowBase + 4,  h);
        float p2 = bperm_f(lowBase + 8,  h);
        float p3 = bperm_f(lowBase + 12, h);
        float i0 = isL0 ? xt : p0;   // p1..p3 hit zero weights on layer 0

        f32x2 aif = bif, ago = bgo;
        f32x2 s2;
        // hh part first (available immediately after DPP), input part after bpermute
        s2 = {h0, h0}; aif += wif[4] * s2; ago += wgo[4] * s2;
        s2 = {h1, h1}; aif += wif[5] * s2; ago += wgo[5] * s2;
        s2 = {h2, h2}; aif += wif[6] * s2; ago += wgo[6] * s2;
        s2 = {h3, h3}; aif += wif[7] * s2; ago += wgo[7] * s2;
        s2 = {i0, i0}; aif += wif[0] * s2; ago += wgo[0] * s2;
        s2 = {p1, p1}; aif += wif[1] * s2; ago += wgo[1] * s2;
        s2 = {p2, p2}; aif += wif[2] * s2; ago += wgo[2] * s2;
        s2 = {p3, p3}; aif += wif[3] * s2; ago += wgo[3] * s2;

        float gi = sigm_f(aif.x);
        float gf = sigm_f(aif.y);
        float gg = tanh_f(ago.x);
        float go = sigm_f(ago.y);
        float cn = __builtin_fmaf(gi, gg, gf * c);
        float hn = go * tanh_f(cn);
        c = active ? cn : c;
        h = active ? hn : h;
    };

    // x chunk prefetch: 64 values per chunk, broadcast via v_readlane
    float xv    = x[lane];
    float xnext = x[64 + lane];

    // ---- chunk 0: pipeline skew-in, predicated (layer l starts at s=l) ----
    #pragma unroll 4
    for (int i = 0; i < 64; ++i) {
        float xt = readlane_f(xv, i);
        doStep(xt, i >= L);
    }
    xv = xnext;

    // ---- main chunks: all layers active, no predication ----
    for (int chunk = 1; chunk < NCHUNK; ++chunk) {
        float xn = 0.0f;
        if (chunk + 1 < NCHUNK) xn = x[(chunk + 1) * 64 + lane];  // prefetch
        #pragma unroll 4
        for (int i = 0; i < 64; ++i) {
            float xt = readlane_f(xv, i);
            doStep(xt, true);
        }
        xv = xn;
    }

    // ---- skew-out: 9 predicated steps (layer l runs through s = l+T-1) ----
    #pragma unroll
    for (int e = 1; e <= 9; ++e) {
        doStep(0.0f, L >= e);
    }

    // ---- final FC: out[k] = W_fc[k,:] . h.flatten() + b_fc[k] ----
    hFinal[lane] = h;
    __syncthreads();
    if (lane < 4) {
        float acc = b_fc[lane];
        #pragma unroll
        for (int p = 0; p < 40; ++p)
            acc = __builtin_fmaf(W_fc[lane * 40 + p], hFinal[p], acc);
        out[lane] = acc;
    }
}

extern "C" void kernel_launch(void* const* d_in, const int* in_sizes, int n_in,
                              void* d_out, int out_size, void* d_ws, size_t ws_size,
                              hipStream_t stream)
{
    const float* x     = (const float*)d_in[0];
    const float* W_ih0 = (const float*)d_in[1];
    const float* W_ih  = (const float*)d_in[2];
    const float* W_hh  = (const float*)d_in[3];
    const float* b_ih  = (const float*)d_in[4];
    const float* b_hh  = (const float*)d_in[5];
    const float* W_fc  = (const float*)d_in[6];
    const float* b_fc  = (const float*)d_in[7];
    float* out = (float*)d_out;

    lstm10_h4_kernel<<<1, 64, 0, stream>>>(x, W_ih0, W_ih, W_hh, b_ih, b_hh,
                                           W_fc, b_fc, out);
}

// Round 2
// 33059.265 us; speedup vs baseline: 1.1126x; 1.1126x over previous
//
#include <hip/hip_runtime.h>

typedef float f32x2 __attribute__((ext_vector_type(2)));

static constexpr int T_LEN  = 262144;
static constexpr int NCHUNK = T_LEN / 64;   // 4096

__device__ __forceinline__ float readlane_f(float v, int srcLane) {
    return __builtin_bit_cast(float, __builtin_amdgcn_readlane(__builtin_bit_cast(int, v), srcLane));
}
__device__ __forceinline__ float bperm_f(int byteAddr, float v) {
    return __builtin_bit_cast(float, __builtin_amdgcn_ds_bpermute(byteAddr, __builtin_bit_cast(int, v)));
}
template <int CTRL>
__device__ __forceinline__ float qperm_f(float v) {
    // DPP quad_perm broadcast within each 4-lane group
    return __builtin_bit_cast(float, __builtin_amdgcn_update_dpp(
        0, __builtin_bit_cast(int, v), CTRL, 0xF, 0xF, true));
}

__global__ __launch_bounds__(64, 1)
void lstm10_h4_kernel(const float* __restrict__ x,
                      const float* __restrict__ W_ih0,
                      const float* __restrict__ W_ih,
                      const float* __restrict__ W_hh,
                      const float* __restrict__ b_ih,
                      const float* __restrict__ b_hh,
                      const float* __restrict__ W_fc,
                      const float* __restrict__ b_fc,
                      float* __restrict__ out)
{
    __shared__ float hFinal[64];

    const int lane = threadIdx.x;
    const int L  = lane >> 2;            // layer 0..15 (10..15 are scratch lanes)
    const int j  = lane & 3;             // hidden unit
    const int Lc = (L < 10) ? L : 9;     // clamp for weight loads (scratch lanes)
    const bool isL0 = (L == 0);
    const int twoL = 2 * L;              // 2-step systolic skew

    // gate rows for hidden unit j: i=rows[0:4], f=[4:8], g=[8:12], o=[12:16]
    const int ri = j, rf = 4 + j, rg = 8 + j, ro = 12 + j;

    // Activation pre-scales folded into weights/biases:
    //  sigmoid(a) = rcp(1 + exp2(SIF*a)),  SIF = -log2(e)
    //  tanh(a)    = 1 - 2*rcp(1 + exp2(SG*a)), SG = 2*log2(e)
    const float SIF = -1.4426950408889634f;
    const float SG  =  2.8853900817779268f;

    // Packed prescaled weights: wif[k] = {SIF*W[i_row][k], SIF*W[f_row][k]}
    //                           wgo[k] = {SG*W[g_row][k], SIF*W[o_row][k]}
    // k = 0..3 input cols, 4..7 hidden (hh) cols
    f32x2 wif[8], wgo[8];
    if (Lc == 0) {
        wif[0] = {SIF * W_ih0[ri], SIF * W_ih0[rf]};
        wgo[0] = {SG  * W_ih0[rg], SIF * W_ih0[ro]};
        #pragma unroll
        for (int k = 1; k < 4; ++k) { wif[k] = {0.f, 0.f}; wgo[k] = {0.f, 0.f}; }
    } else {
        const float* B = W_ih + (Lc - 1) * 64;
        #pragma unroll
        for (int k = 0; k < 4; ++k) {
            wif[k] = {SIF * B[ri*4+k], SIF * B[rf*4+k]};
            wgo[k] = {SG  * B[rg*4+k], SIF * B[ro*4+k]};
        }
    }
    {
        const float* B = W_hh + Lc * 64;
        #pragma unroll
        for (int k = 0; k < 4; ++k) {
            wif[4+k] = {SIF * B[ri*4+k], SIF * B[rf*4+k]};
            wgo[4+k] = {SG  * B[rg*4+k], SIF * B[ro*4+k]};
        }
    }
    const float* bi = b_ih + Lc * 16;
    const float* bh = b_hh + Lc * 16;
    f32x2 bif = {SIF * (bi[ri] + bh[ri]), SIF * (bi[rf] + bh[rf])};
    f32x2 bgo = {SG  * (bi[rg] + bh[rg]), SIF * (bi[ro] + bh[ro])};

    // bpermute byte-address of lane 4*(L-1) (lower layer's quad)
    const int lowBase = ((L > 0 ? L - 1 : 0) * 4) << 2;

    float c = 0.0f, h = 0.0f;

    // Double-buffered prefetched lower-layer h (2-iteration skew):
    // even iters consume & refill {a0..a3}; odd iters {b0..b3}.
    float a0 = 0.f, a1 = 0.f, a2 = 0.f, a3 = 0.f;
    float b0 = 0.f, b1 = 0.f, b2 = 0.f, b3 = 0.f;

    auto doStep = [&](float xt, bool active,
                      float& p0, float& p1, float& p2, float& p3) {
        float i0 = isL0 ? xt : p0;

        // ---- input part: independent of current h (p* prefetched 2 iters ago)
        f32x2 s;
        f32x2 accI = bif, accG = bgo;
        s = {i0, i0}; accI += wif[0] * s; accG += wgo[0] * s;
        s = {p1, p1}; accI += wif[1] * s; accG += wgo[1] * s;
        s = {p2, p2}; accI += wif[2] * s; accG += wgo[2] * s;
        s = {p3, p3}; accI += wif[3] * s; accG += wgo[3] * s;

        // ---- hh part: tree-structured off the own-h broadcast
        float s0 = qperm_f<0x00>(h);
        float s1 = qperm_f<0x55>(h);
        float s2 = qperm_f<0xAA>(h);
        float s3 = qperm_f<0xFF>(h);
        f32x2 v0 = {s0, s0}, v1 = {s1, s1}, v2 = {s2, s2}, v3 = {s3, s3};
        f32x2 uI = accI + wif[4] * v0;  uI += wif[5] * v1;   // chain off accI
        f32x2 tI = wif[6] * v2;         tI += wif[7] * v3;   // parallel chain
        f32x2 uG = accG + wgo[4] * v0;  uG += wgo[5] * v1;
        f32x2 tG = wgo[6] * v2;         tG += wgo[7] * v3;
        f32x2 aif = uI + tI;
        f32x2 ago = uG + tG;

        // ---- activations (prescaled args)
        float gi = __builtin_amdgcn_rcpf(1.0f + __builtin_amdgcn_exp2f(aif.x));
        float gf = __builtin_amdgcn_rcpf(1.0f + __builtin_amdgcn_exp2f(aif.y));
        float rg = __builtin_amdgcn_rcpf(1.0f + __builtin_amdgcn_exp2f(ago.x));
        float go = __builtin_amdgcn_rcpf(1.0f + __builtin_amdgcn_exp2f(ago.y));
        float gg = __builtin_fmaf(-2.0f, rg, 1.0f);          // tanh(g)

        float cn = __builtin_fmaf(gi, gg, gf * c);
        float tc = __builtin_amdgcn_rcpf(1.0f + __builtin_amdgcn_exp2f(SG * cn));
        float hn = go * __builtin_fmaf(-2.0f, tc, 1.0f);

        c = active ? cn : c;
        h = active ? hn : h;

        // ---- prefetch lower-layer h for iteration s+2 (latency hidden)
        p0 = bperm_f(lowBase + 0,  h);
        p1 = bperm_f(lowBase + 4,  h);
        p2 = bperm_f(lowBase + 8,  h);
        p3 = bperm_f(lowBase + 12, h);
    };

    // x chunk prefetch: 64 values per chunk, broadcast via v_readlane
    float xv    = x[lane];
    float xnext = x[64 + lane];

    // ---- chunk 0: pipeline skew-in, predicated (layer l starts at s=2l) ----
    #pragma unroll 4
    for (int ii = 0; ii < 32; ++ii) {
        int i0 = 2 * ii, i1 = 2 * ii + 1;
        doStep(readlane_f(xv, i0), i0 >= twoL, a0, a1, a2, a3);
        doStep(readlane_f(xv, i1), i1 >= twoL, b0, b1, b2, b3);
    }
    xv = xnext;

    // ---- main chunks: all layers active, no predication ----
    for (int chunk = 1; chunk < NCHUNK; ++chunk) {
        float xn = 0.0f;
        if (chunk + 1 < NCHUNK) xn = x[(chunk + 1) * 64 + lane];  // prefetch
        #pragma unroll 8
        for (int ii = 0; ii < 32; ++ii) {
            doStep(readlane_f(xv, 2 * ii),     true, a0, a1, a2, a3);
            doStep(readlane_f(xv, 2 * ii + 1), true, b0, b1, b2, b3);
        }
        xv = xn;
    }

    // ---- skew-out: 18 predicated steps (layer l runs through s = 2l+T-1) ----
    #pragma unroll
    for (int ee = 0; ee < 9; ++ee) {
        doStep(0.0f, twoL >= 2 * ee + 1, a0, a1, a2, a3);
        doStep(0.0f, twoL >= 2 * ee + 2, b0, b1, b2, b3);
    }

    // ---- final FC: out[k] = W_fc[k,:] . h.flatten() + b_fc[k] ----
    hFinal[lane] = h;
    __syncthreads();
    if (lane < 4) {
        float acc = b_fc[lane];
        #pragma unroll
        for (int p = 0; p < 40; ++p)
            acc = __builtin_fmaf(W_fc[lane * 40 + p], hFinal[p], acc);
        out[lane] = acc;
    }
}

extern "C" void kernel_launch(void* const* d_in, const int* in_sizes, int n_in,
                              void* d_out, int out_size, void* d_ws, size_t ws_size,
                              hipStream_t stream)
{
    const float* x     = (const float*)d_in[0];
    const float* W_ih0 = (const float*)d_in[1];
    const float* W_ih  = (const float*)d_in[2];
    const float* W_hh  = (const float*)d_in[3];
    const float* b_ih  = (const float*)d_in[4];
    const float* b_hh  = (const float*)d_in[5];
    const float* W_fc  = (const float*)d_in[6];
    const float* b_fc  = (const float*)d_in[7];
    float* out = (float*)d_out;

    lstm10_h4_kernel<<<1, 64, 0, stream>>>(x, W_ih0, W_ih, W_hh, b_ih, b_hh,
                                           W_fc, b_fc, out);
}